// Round 4
// baseline (1744.834 us; speedup 1.0000x reference)
//
#include <hip/hip_runtime.h>
#include <hip/hip_bf16.h>

// Problem constants
#define BB 2
#define L2C 4
#define N2C 2048
#define L1C 9
#define N1C 8192
#define CINC 128
#define CTC 128
#define CSC 256
#define CORIGC 64
#define KC 3

// d_out (f32): [original_xyzs 442368] then [new_features (B,L1,CS,N1) 37748736]
#define OUT_XYZ_SIZE (BB*L1C*N1C*3)

#define SLICE_ELEMS (KC*N2C*CTC)        // 786432 floats per (b,l2) tt slice
#define FLT_BIG     3.402823466e38f

__device__ __forceinline__ float d2_exact(float dx, float dy, float dz) {
    #pragma clang fp contract(off)
    return (dx * dx + dy * dy) + dz * dz;
}

// ---------------------------------------------------------------------------
// Kernel P: fold BN into scale/shift (bnp[0..255]=scale, bnp[256..511]=shift)
__global__ __launch_bounds__(256) void prep_kernel(const float* __restrict__ gam,
                                                   const float* __restrict__ bet,
                                                   const float* __restrict__ mu,
                                                   const float* __restrict__ var,
                                                   float* __restrict__ bnp) {
    int o = threadIdx.x;
    float sc = gam[o] / sqrtf(var[o] + 1e-5f);
    bnp[o]       = sc;
    bnp[CSC + o] = bet[o] - mu[o] * sc;
}

// ---------------------------------------------------------------------------
// Kernel 1: tt = relu(Wt1[k] @ relu(Wt0[k] @ features[b,l2])), one slice per
// blockIdx.y, stored tt_out[slice][k][n2][c] (f32). grid (64, nslices).
__global__ __launch_bounds__(256) void tt_kernel(const float* __restrict__ feat,
                                                 const float* __restrict__ Wt0,
                                                 const float* __restrict__ Wt1,
                                                 float* __restrict__ tt_out,
                                                 int bl_base) {
    __shared__ __align__(16) float ft[32][132];
    __shared__ __align__(16) float ht[32][132];
    __shared__ __align__(16) float ot[32][132];
    const int t  = threadIdx.x;
    const int bl = bl_base + blockIdx.y;     // absolute b*L2 + l2
    const int n0 = blockIdx.x * 32;

    const float* f = feat + (size_t)bl * CINC * N2C;
    for (int i = 0; i < 16; ++i) {
        int idx = i * 256 + t;
        int c = idx >> 5, n = idx & 31;
        ft[n][c] = f[(size_t)c * N2C + n0 + n];
    }
    __syncthreads();

    const int n  = t & 31;
    const int og = t >> 5;
    float* ttg = tt_out + (size_t)blockIdx.y * SLICE_ELEMS;

    for (int k = 0; k < KC; ++k) {
        {
            const float* W0 = Wt0 + (size_t)k * CTC * CINC;
            for (int ob = 0; ob < 4; ++ob) {
                int o0 = og * 16 + ob * 4;
                const float* wr = W0 + (size_t)o0 * CINC;
                float a0 = 0.f, a1 = 0.f, a2 = 0.f, a3 = 0.f;
                for (int c = 0; c < CINC; c += 4) {
                    float4 fv = *(const float4*)&ft[n][c];
                    float4 wA = *(const float4*)(wr + c);
                    float4 wB = *(const float4*)(wr + CINC + c);
                    float4 wC = *(const float4*)(wr + 2 * CINC + c);
                    float4 wD = *(const float4*)(wr + 3 * CINC + c);
                    a0 += wA.x * fv.x + wA.y * fv.y + wA.z * fv.z + wA.w * fv.w;
                    a1 += wB.x * fv.x + wB.y * fv.y + wB.z * fv.z + wB.w * fv.w;
                    a2 += wC.x * fv.x + wC.y * fv.y + wC.z * fv.z + wC.w * fv.w;
                    a3 += wD.x * fv.x + wD.y * fv.y + wD.z * fv.z + wD.w * fv.w;
                }
                ht[n][o0 + 0] = fmaxf(a0, 0.f);
                ht[n][o0 + 1] = fmaxf(a1, 0.f);
                ht[n][o0 + 2] = fmaxf(a2, 0.f);
                ht[n][o0 + 3] = fmaxf(a3, 0.f);
            }
        }
        __syncthreads();
        {
            const float* W1 = Wt1 + (size_t)k * CTC * CTC;
            for (int ob = 0; ob < 4; ++ob) {
                int o0 = og * 16 + ob * 4;
                const float* wr = W1 + (size_t)o0 * CTC;
                float a0 = 0.f, a1 = 0.f, a2 = 0.f, a3 = 0.f;
                for (int c = 0; c < CTC; c += 4) {
                    float4 fv = *(const float4*)&ht[n][c];
                    float4 wA = *(const float4*)(wr + c);
                    float4 wB = *(const float4*)(wr + CTC + c);
                    float4 wC = *(const float4*)(wr + 2 * CTC + c);
                    float4 wD = *(const float4*)(wr + 3 * CTC + c);
                    a0 += wA.x * fv.x + wA.y * fv.y + wA.z * fv.z + wA.w * fv.w;
                    a1 += wB.x * fv.x + wB.y * fv.y + wB.z * fv.z + wB.w * fv.w;
                    a2 += wC.x * fv.x + wC.y * fv.y + wC.z * fv.z + wC.w * fv.w;
                    a3 += wD.x * fv.x + wD.y * fv.y + wD.z * fv.z + wD.w * fv.w;
                }
                ot[n][o0 + 0] = fmaxf(a0, 0.f);
                ot[n][o0 + 1] = fmaxf(a1, 0.f);
                ot[n][o0 + 2] = fmaxf(a2, 0.f);
                ot[n][o0 + 3] = fmaxf(a3, 0.f);
            }
        }
        __syncthreads();
        {
            float* dst = ttg + (size_t)k * N2C * CTC;
            for (int i = 0; i < 16; ++i) {
                int idx = i * 256 + t;
                int nn = idx >> 7, o = idx & 127;
                dst[(size_t)(n0 + nn) * CTC + o] = ot[nn][o];
            }
        }
        __syncthreads();
    }
}

// ---------------------------------------------------------------------------
// Kernel 2: brute-force 3-NN per anchor (np-exact d2 + tie semantics).
// grid (32, nbt1). kio offsets are element offsets into the tt buffer whose
// slice numbering starts at `abs_mode ? b*L2+t2min : 0`.
__global__ __launch_bounds__(256) void knn_kernel(const float* __restrict__ xyzs,
                                                  const float* __restrict__ oxyz,
                                                  int* __restrict__ kio,
                                                  float* __restrict__ kw,
                                                  int bt1_base, int kio_stride, int abs_mode) {
    __shared__ __align__(16) float sx[4096];
    __shared__ __align__(16) float sy[4096];
    __shared__ __align__(16) float sz[4096];
    const int t   = threadIdx.x;
    const int bt1 = bt1_base + blockIdx.y;
    const int b   = bt1 / L1C;
    const int t1  = bt1 % L1C + 1;
    int t2min = (t1 - 2) >> 1; if (t2min < 0) t2min = 0;
    int t2max = (t1 - 1) >> 1; if (t2max > 3) t2max = 3;
    const int S = (t2max - t2min + 1) * N2C;

    for (int s = t; s < S; s += 256) {
        int t2 = t2min + (s >> 11);
        int n2 = s & 2047;
        const float* p = xyzs + ((size_t)(b * L2C + t2) * N2C + n2) * 3;
        sx[s] = p[0]; sy[s] = p[1]; sz[s] = p[2];
    }
    __syncthreads();

    const int n1 = blockIdx.x * 256 + t;
    const float* a = oxyz + ((size_t)bt1 * N1C + n1) * 3;
    const float ax = a[0], ay = a[1], az = a[2];

    float b0 = FLT_BIG, b1 = FLT_BIG, b2 = FLT_BIG;
    int   i0 = 0, i1 = 0, i2 = 0;

    for (int s = 0; s < S; ++s) {
        float d2v = d2_exact(ax - sx[s], ay - sy[s], az - sz[s]);
        if (d2v < b2) {
            if (d2v < b1) {
                b2 = b1; i2 = i1;
                if (d2v < b0) { b1 = b0; i1 = i0; b0 = d2v; i0 = s; }
                else          { b1 = d2v; i1 = s; }
            } else { b2 = d2v; i2 = s; }
        }
    }

    float w0 = 1.f / (b0 + 1e-8f);
    float w1 = 1.f / (b1 + 1e-8f);
    float w2 = 1.f / (b2 + 1e-8f);
    float wsum = (w0 + w1) + w2;

    const int slice0 = abs_mode ? (b * L2C + t2min) : 0;
    size_t base = (size_t)blockIdx.y * kio_stride + (size_t)n1 * 3;
    int   ss[3] = { i0, i1, i2 };
    float wv[3] = { w0 / wsum, w1 / wsum, w2 / wsum };
    #pragma unroll
    for (int j = 0; j < 3; ++j) {
        int s   = ss[j];
        int rel = s >> 11;               // t2 - t2min
        int n2  = s & 2047;
        int t2  = t2min + rel;
        int kidx = t1 - 2 * t2 - 1;
        kio[base + j] = ((slice0 + rel) * KC + kidx) * (N2C * CTC) + n2 * CTC;
        kw[base + j]  = wv[j];
    }
}

// ---------------------------------------------------------------------------
// Kernel 3: gather-interp + concat + GEMM(256x192) + BN + ReLU. grid (128, nbt1).
__global__ __launch_bounds__(256) void out_kernel(const float* __restrict__ ofeat,
                                                  const float* __restrict__ Wsm,
                                                  const float* __restrict__ tt,
                                                  const int* __restrict__ kio,
                                                  const float* __restrict__ kw,
                                                  const float* __restrict__ bnp,
                                                  float* __restrict__ out,
                                                  int bt1_base, int kio_stride) {
    __shared__ __align__(16) float xt[64][196];
    const int t   = threadIdx.x;
    const int bt1 = bt1_base + blockIdx.y;
    const int n0  = blockIdx.x * 64;

    // interp rows (c in 0..127): one wave per n, lanes = channels
    {
        const int w    = t >> 6;
        const int lane = t & 63;
        for (int nn = 0; nn < 16; ++nn) {
            int n = w * 16 + nn;
            size_t kbase = (size_t)blockIdx.y * kio_stride + (size_t)(n0 + n) * 3;
            int   o0 = kio[kbase], o1 = kio[kbase + 1], o2 = kio[kbase + 2];
            float q0 = kw[kbase],  q1 = kw[kbase + 1],  q2 = kw[kbase + 2];
            float v0 = (tt[o0 + lane] * q0 + tt[o1 + lane] * q1) + tt[o2 + lane] * q2;
            float v1 = (tt[o0 + 64 + lane] * q0 + tt[o1 + 64 + lane] * q1)
                     + tt[o2 + 64 + lane] * q2;
            xt[n][lane]      = v0;
            xt[n][64 + lane] = v1;
        }
    }
    // original_features rows (c in 128..191)
    {
        const float* ofp = ofeat + (size_t)bt1 * CORIGC * N1C;
        for (int i = 0; i < 16; ++i) {
            int idx = i * 256 + t;
            int cp = idx >> 6, n = idx & 63;
            xt[n][CTC + cp] = ofp[(size_t)cp * N1C + n0 + n];
        }
    }
    __syncthreads();

    const int n  = t & 63;
    const int og = t >> 6;
    float* outp = out + OUT_XYZ_SIZE + (size_t)bt1 * CSC * N1C;

    for (int ob = 0; ob < 16; ++ob) {
        int o0 = og * 64 + ob * 4;
        const float* wr = Wsm + (size_t)o0 * 192;
        float a0 = 0.f, a1 = 0.f, a2 = 0.f, a3 = 0.f;
        for (int c = 0; c < 192; c += 4) {
            float4 fv = *(const float4*)&xt[n][c];
            float4 wA = *(const float4*)(wr + c);
            float4 wB = *(const float4*)(wr + 192 + c);
            float4 wC = *(const float4*)(wr + 384 + c);
            float4 wD = *(const float4*)(wr + 576 + c);
            a0 += wA.x * fv.x + wA.y * fv.y + wA.z * fv.z + wA.w * fv.w;
            a1 += wB.x * fv.x + wB.y * fv.y + wB.z * fv.z + wB.w * fv.w;
            a2 += wC.x * fv.x + wC.y * fv.y + wC.z * fv.z + wC.w * fv.w;
            a3 += wD.x * fv.x + wD.y * fv.y + wD.z * fv.z + wD.w * fv.w;
        }
        float y0 = fmaxf(a0 * bnp[o0 + 0] + bnp[CSC + o0 + 0], 0.f);
        float y1 = fmaxf(a1 * bnp[o0 + 1] + bnp[CSC + o0 + 1], 0.f);
        float y2 = fmaxf(a2 * bnp[o0 + 2] + bnp[CSC + o0 + 2], 0.f);
        float y3 = fmaxf(a3 * bnp[o0 + 3] + bnp[CSC + o0 + 3], 0.f);
        outp[(size_t)(o0 + 0) * N1C + n0 + n] = y0;
        outp[(size_t)(o0 + 1) * N1C + n0 + n] = y1;
        outp[(size_t)(o0 + 2) * N1C + n0 + n] = y2;
        outp[(size_t)(o0 + 3) * N1C + n0 + n] = y3;
    }
}

// ---------------------------------------------------------------------------
extern "C" void kernel_launch(void* const* d_in, const int* in_sizes, int n_in,
                              void* d_out, int out_size, void* d_ws, size_t ws_size,
                              hipStream_t stream) {
    const float* xyzs  = (const float*)d_in[0];
    const float* oxyz  = (const float*)d_in[1];
    const float* feat  = (const float*)d_in[2];
    const float* ofeat = (const float*)d_in[3];
    const float* Wt0   = (const float*)d_in[4];
    const float* Wt1   = (const float*)d_in[5];
    const float* Wsm   = (const float*)d_in[6];
    const float* gam   = (const float*)d_in[7];
    const float* bet   = (const float*)d_in[8];
    const float* mu    = (const float*)d_in[9];
    const float* var   = (const float*)d_in[10];
    float* out = (float*)d_out;
    float* ws  = (float*)d_ws;

    // Output 0: exact passthrough
    hipMemcpyAsync(out, oxyz, (size_t)OUT_XYZ_SIZE * sizeof(float),
                   hipMemcpyDeviceToDevice, stream);

    const size_t TT_FULL  = (size_t)BB * L2C * SLICE_ELEMS;   // 6,291,456 floats
    const size_t KI_FULL  = (size_t)BB * L1C * N1C * 3;       //   442,368
    const size_t need_T1  = (TT_FULL + 2 * KI_FULL + 2 * CSC) * 4;        // 28,706,816 B

    if (ws_size >= need_T1) {
        // ---- T1: full tt materialization, one pass ----
        float* tt  = ws;
        int*   kio = (int*)(ws + TT_FULL);
        float* kw  = ws + TT_FULL + KI_FULL;
        float* bnp = ws + TT_FULL + 2 * KI_FULL;

        hipLaunchKernelGGL(prep_kernel, dim3(1), dim3(256), 0, stream, gam, bet, mu, var, bnp);
        hipLaunchKernelGGL(tt_kernel, dim3(64, BB * L2C), dim3(256), 0, stream,
                           feat, Wt0, Wt1, tt, 0);
        hipLaunchKernelGGL(knn_kernel, dim3(32, BB * L1C), dim3(256), 0, stream,
                           xyzs, oxyz, kio, kw, 0, N1C * 3, 1);
        hipLaunchKernelGGL(out_kernel, dim3(128, BB * L1C), dim3(256), 0, stream,
                           ofeat, Wsm, tt, kio, kw, bnp, out, 0, N1C * 3);
    } else {
        // ---- T3: stream per (b,t1); tt recomputed for the <=2 needed slices ----
        float* tt  = ws;                                   // 2 slices max
        int*   kio = (int*)(ws + 2 * SLICE_ELEMS);
        float* kw  = ws + 2 * SLICE_ELEMS + (size_t)N1C * 3;
        float* bnp = ws + 2 * SLICE_ELEMS + (size_t)N1C * 6;

        hipLaunchKernelGGL(prep_kernel, dim3(1), dim3(256), 0, stream, gam, bet, mu, var, bnp);
        for (int bt1 = 0; bt1 < BB * L1C; ++bt1) {
            int b  = bt1 / L1C;
            int t1 = bt1 % L1C + 1;
            int t2min = (t1 - 2) >> 1; if (t2min < 0) t2min = 0;
            int t2max = (t1 - 1) >> 1; if (t2max > 3) t2max = 3;
            int nsl = t2max - t2min + 1;
            hipLaunchKernelGGL(tt_kernel, dim3(64, nsl), dim3(256), 0, stream,
                               feat, Wt0, Wt1, tt, b * L2C + t2min);
            hipLaunchKernelGGL(knn_kernel, dim3(32, 1), dim3(256), 0, stream,
                               xyzs, oxyz, kio, kw, bt1, 0, 0);
            hipLaunchKernelGGL(out_kernel, dim3(128, 1), dim3(256), 0, stream,
                               ofeat, Wsm, tt, kio, kw, bnp, out, bt1, 0);
        }
    }
}

// Round 5
// 790.862 us; speedup vs baseline: 2.2062x; 2.2062x over previous
//
#include <hip/hip_runtime.h>
#include <hip/hip_bf16.h>
#include <hip/hip_fp16.h>

// Problem constants
#define BB 2
#define L2C 4
#define N2C 2048
#define L1C 9
#define N1C 8192
#define CINC 128
#define CTC 128
#define CSC 256
#define CORIGC 64
#define KC 3

#define OUT_XYZ_SIZE (BB*L1C*N1C*3)
#define FLT_BIG     3.402823466e38f

typedef __attribute__((ext_vector_type(8))) short bf16x8;
typedef __attribute__((ext_vector_type(4))) float f32x4;

#define MFMA16(a,b,c) __builtin_amdgcn_mfma_f32_16x16x32_bf16((a),(b),(c),0,0,0)

// ws layout (bytes):
//  tt   f32      @ 0          : 6,291,456 * 4 = 25,165,824
//  nbr  u32      @ 25,165,824 :   442,368 * 4 =  1,769,472   (idx16<<16 | half(w))
//  WsH/WsL/W0H/W0L/W1H/W1L bf16 @ 26,935,296 : 6 * 49,152 * 2 = 589,824
//  bnp  f32[512] @ 27,525,120 : 2,048
//  total 27,527,168  (< 28,706,816 proven available in R4)
#define WS_TT_OFF   0
#define WS_NBR_OFF  25165824
#define WS_W_OFF    26935296
#define WS_BNP_OFF  27525120

__device__ __forceinline__ unsigned short bf16_hi(float v) {
    __hip_bfloat16 h = __float2bfloat16(v);
    return *(unsigned short*)&h;
}
__device__ __forceinline__ float bf16_to_f(unsigned short u) {
    unsigned int x = ((unsigned int)u) << 16;
    return __uint_as_float(x);
}
__device__ __forceinline__ float d2_exact(float dx, float dy, float dz) {
    #pragma clang fp contract(off)
    return (dx * dx + dy * dy) + dz * dz;
}

// ---------------------------------------------------------------------------
// Kernel P: hi/lo bf16 splits of Ws/Wt0/Wt1 (each 49152 elems) + BN fold.
__global__ __launch_bounds__(256) void prep_kernel(const float* __restrict__ Wsm,
                                                   const float* __restrict__ Wt0,
                                                   const float* __restrict__ Wt1,
                                                   const float* __restrict__ gam,
                                                   const float* __restrict__ bet,
                                                   const float* __restrict__ mu,
                                                   const float* __restrict__ var,
                                                   unsigned short* __restrict__ WsH,
                                                   unsigned short* __restrict__ WsL,
                                                   unsigned short* __restrict__ W0H,
                                                   unsigned short* __restrict__ W0L,
                                                   unsigned short* __restrict__ W1H,
                                                   unsigned short* __restrict__ W1L,
                                                   float* __restrict__ bnp) {
    for (int i = blockIdx.x * 256 + threadIdx.x; i < 49152; i += gridDim.x * 256) {
        float a = Wsm[i]; unsigned short h = bf16_hi(a);
        WsH[i] = h; WsL[i] = bf16_hi(a - bf16_to_f(h));
        float b = Wt0[i]; h = bf16_hi(b);
        W0H[i] = h; W0L[i] = bf16_hi(b - bf16_to_f(h));
        float c = Wt1[i]; h = bf16_hi(c);
        W1H[i] = h; W1L[i] = bf16_hi(c - bf16_to_f(h));
    }
    if (blockIdx.x == 0) {
        int o = threadIdx.x;
        float sc = gam[o] / sqrtf(var[o] + 1e-5f);
        bnp[o]       = sc;
        bnp[CSC + o] = bet[o] - mu[o] * sc;
    }
}

// ---------------------------------------------------------------------------
// Kernel 1 (MFMA): tt[slice][k][n2][c] = relu(W1[k] @ relu(W0[k] @ feat[slice]))
// grid (32 n-tiles of 64, 8 slices), 256 thr = 4 waves. M=o, N=n2.
// LDS K-blocked layout: elem(c,n) at ((c>>3)*64 + n)*8 + (c&7)  (zero pad, bank-floor)
__global__ __launch_bounds__(256) void tt_kernel(const float* __restrict__ feat,
                                                 const unsigned short* __restrict__ W0H,
                                                 const unsigned short* __restrict__ W0L,
                                                 const unsigned short* __restrict__ W1H,
                                                 const unsigned short* __restrict__ W1L,
                                                 float* __restrict__ tt) {
    __shared__ unsigned short Bh[16 * 64 * 8];   // feat tile hi  (16 KB)
    __shared__ unsigned short Bl[16 * 64 * 8];   // feat tile lo
    __shared__ unsigned short Hh[16 * 64 * 8];   // layer-1 output hi
    const int t     = threadIdx.x;
    const int slice = blockIdx.y;
    const int n0    = blockIdx.x * 64;
    const int lane  = t & 63;
    const int w     = t >> 6;
    const int l15   = lane & 15;
    const int quad  = lane >> 4;

    // stage feat[slice][c][n0..n0+63] -> Bh/Bl blocked
    const float* f = feat + (size_t)slice * CINC * N2C;
    for (int i = 0; i < 32; ++i) {
        int idx = i * 256 + t;
        int c = idx >> 6, n = idx & 63;
        float v = f[(size_t)c * N2C + n0 + n];
        unsigned short h = bf16_hi(v);
        int bi = (((c >> 3) * 64) + n) * 8 + (c & 7);
        Bh[bi] = h;
        Bl[bi] = bf16_hi(v - bf16_to_f(h));
    }
    __syncthreads();

    float* ttg = tt + (size_t)slice * KC * N2C * CTC;
    const f32x4 zero = {0.f, 0.f, 0.f, 0.f};

    for (int k = 0; k < KC; ++k) {
        // ---- layer 1: o in [32w, 32w+32), all 64 n ----
        f32x4 acc[2][4];
        for (int oi = 0; oi < 2; ++oi)
            for (int ni = 0; ni < 4; ++ni) acc[oi][ni] = zero;
        {
            const unsigned short* AH = W0H + (size_t)k * CTC * CINC;
            const unsigned short* AL = W0L + (size_t)k * CTC * CINC;
            for (int kst = 0; kst < 4; ++kst) {
                bf16x8 ah[2], al[2], bh[4], bl[4];
                #pragma unroll
                for (int oi = 0; oi < 2; ++oi) {
                    int o = 32 * w + oi * 16 + l15;
                    ah[oi] = *(const bf16x8*)(AH + (size_t)o * CINC + kst * 32 + quad * 8);
                    al[oi] = *(const bf16x8*)(AL + (size_t)o * CINC + kst * 32 + quad * 8);
                }
                #pragma unroll
                for (int ni = 0; ni < 4; ++ni) {
                    int n = ni * 16 + l15;
                    int c8 = kst * 4 + quad;
                    bh[ni] = *(const bf16x8*)&Bh[(c8 * 64 + n) * 8];
                    bl[ni] = *(const bf16x8*)&Bl[(c8 * 64 + n) * 8];
                }
                #pragma unroll
                for (int oi = 0; oi < 2; ++oi)
                    #pragma unroll
                    for (int ni = 0; ni < 4; ++ni) {
                        acc[oi][ni] = MFMA16(ah[oi], bh[ni], acc[oi][ni]);
                        acc[oi][ni] = MFMA16(ah[oi], bl[ni], acc[oi][ni]);
                        acc[oi][ni] = MFMA16(al[oi], bh[ni], acc[oi][ni]);
                    }
            }
        }
        // relu + bf16-hi quantize -> Hh (C-frag rows = 4 consecutive o)
        #pragma unroll
        for (int oi = 0; oi < 2; ++oi)
            #pragma unroll
            for (int ni = 0; ni < 4; ++ni) {
                int n = ni * 16 + l15;
                int obase = 32 * w + oi * 16 + quad * 4;
                int ch = obase >> 3, jj = obase & 7;
                unsigned short* dst = &Hh[(ch * 64 + n) * 8 + jj];
                dst[0] = bf16_hi(fmaxf(acc[oi][ni][0], 0.f));
                dst[1] = bf16_hi(fmaxf(acc[oi][ni][1], 0.f));
                dst[2] = bf16_hi(fmaxf(acc[oi][ni][2], 0.f));
                dst[3] = bf16_hi(fmaxf(acc[oi][ni][3], 0.f));
            }
        __syncthreads();

        // ---- layer 2 ----
        f32x4 acc2[2][4];
        for (int oi = 0; oi < 2; ++oi)
            for (int ni = 0; ni < 4; ++ni) acc2[oi][ni] = zero;
        {
            const unsigned short* AH = W1H + (size_t)k * CTC * CTC;
            const unsigned short* AL = W1L + (size_t)k * CTC * CTC;
            for (int kst = 0; kst < 4; ++kst) {
                bf16x8 ah[2], al[2], bh[4];
                #pragma unroll
                for (int oi = 0; oi < 2; ++oi) {
                    int o = 32 * w + oi * 16 + l15;
                    ah[oi] = *(const bf16x8*)(AH + (size_t)o * CTC + kst * 32 + quad * 8);
                    al[oi] = *(const bf16x8*)(AL + (size_t)o * CTC + kst * 32 + quad * 8);
                }
                #pragma unroll
                for (int ni = 0; ni < 4; ++ni) {
                    int n = ni * 16 + l15;
                    int c8 = kst * 4 + quad;
                    bh[ni] = *(const bf16x8*)&Hh[(c8 * 64 + n) * 8];
                }
                #pragma unroll
                for (int oi = 0; oi < 2; ++oi)
                    #pragma unroll
                    for (int ni = 0; ni < 4; ++ni) {
                        acc2[oi][ni] = MFMA16(ah[oi], bh[ni], acc2[oi][ni]);
                        acc2[oi][ni] = MFMA16(al[oi], bh[ni], acc2[oi][ni]);
                    }
            }
        }
        // relu + f32 store: tt[k][n2][o], 4 consecutive o per lane -> dwordx4
        #pragma unroll
        for (int oi = 0; oi < 2; ++oi)
            #pragma unroll
            for (int ni = 0; ni < 4; ++ni) {
                int n2 = n0 + ni * 16 + l15;
                int obase = 32 * w + oi * 16 + quad * 4;
                f32x4 vv;
                vv[0] = fmaxf(acc2[oi][ni][0], 0.f);
                vv[1] = fmaxf(acc2[oi][ni][1], 0.f);
                vv[2] = fmaxf(acc2[oi][ni][2], 0.f);
                vv[3] = fmaxf(acc2[oi][ni][3], 0.f);
                *(f32x4*)&ttg[((size_t)k * N2C + n2) * CTC + obase] = vv;
            }
        __syncthreads();   // Hh reused next k
    }
}

// ---------------------------------------------------------------------------
// Kernel 2: brute-force 3-NN (np-exact d2 + tie semantics). Packed output:
// nbr[(bt1*N1C+n1)*3+j] = (idx16 << 16) | half(w),  idx16 = tt elem offset / 128
__global__ __launch_bounds__(256) void knn_kernel(const float* __restrict__ xyzs,
                                                  const float* __restrict__ oxyz,
                                                  unsigned int* __restrict__ nbr) {
    __shared__ __align__(16) float sx[4096];
    __shared__ __align__(16) float sy[4096];
    __shared__ __align__(16) float sz[4096];
    const int t   = threadIdx.x;
    const int bt1 = blockIdx.y;
    const int b   = bt1 / L1C;
    const int t1  = bt1 % L1C + 1;
    int t2min = (t1 - 2) >> 1; if (t2min < 0) t2min = 0;
    int t2max = (t1 - 1) >> 1; if (t2max > 3) t2max = 3;
    const int S = (t2max - t2min + 1) * N2C;

    for (int s = t; s < S; s += 256) {
        int t2 = t2min + (s >> 11);
        int n2 = s & 2047;
        const float* p = xyzs + ((size_t)(b * L2C + t2) * N2C + n2) * 3;
        sx[s] = p[0]; sy[s] = p[1]; sz[s] = p[2];
    }
    __syncthreads();

    const int n1 = blockIdx.x * 256 + t;
    const float* a = oxyz + ((size_t)bt1 * N1C + n1) * 3;
    const float ax = a[0], ay = a[1], az = a[2];

    float b0 = FLT_BIG, b1 = FLT_BIG, b2 = FLT_BIG;
    int   i0 = 0, i1 = 0, i2 = 0;
    for (int s = 0; s < S; ++s) {
        float d2v = d2_exact(ax - sx[s], ay - sy[s], az - sz[s]);
        if (d2v < b2) {
            if (d2v < b1) {
                b2 = b1; i2 = i1;
                if (d2v < b0) { b1 = b0; i1 = i0; b0 = d2v; i0 = s; }
                else          { b1 = d2v; i1 = s; }
            } else { b2 = d2v; i2 = s; }
        }
    }

    float w0 = 1.f / (b0 + 1e-8f);
    float w1 = 1.f / (b1 + 1e-8f);
    float w2 = 1.f / (b2 + 1e-8f);
    float wsum = (w0 + w1) + w2;

    size_t base = ((size_t)bt1 * N1C + n1) * 3;
    int   ss[3] = { i0, i1, i2 };
    float wv[3] = { w0 / wsum, w1 / wsum, w2 / wsum };
    #pragma unroll
    for (int j = 0; j < 3; ++j) {
        int s  = ss[j];
        int t2 = t2min + (s >> 11);
        int n2 = s & 2047;
        int kidx = t1 - 2 * t2 - 1;
        unsigned int idx16 = (unsigned int)(((b * L2C + t2) * KC + kidx) * N2C + n2);
        unsigned short hb = __half_as_ushort(__float2half(wv[j]));
        nbr[base + j] = (idx16 << 16) | (unsigned int)hb;
    }
}

// ---------------------------------------------------------------------------
// Kernel 3 (MFMA): gather-interp + concat + GEMM(o=256, k=192) + BN + ReLU.
// grid (128 n-tiles of 64, 18 bt1), 256 thr = 4 waves. M=n1, N=o.
__global__ __launch_bounds__(256) void out_kernel(const float* __restrict__ ofeat,
                                                  const unsigned short* __restrict__ WsH,
                                                  const unsigned short* __restrict__ WsL,
                                                  const float* __restrict__ tt,
                                                  const unsigned int* __restrict__ nbr,
                                                  const float* __restrict__ bnp,
                                                  float* __restrict__ out) {
    __shared__ unsigned short xh[24 * 64 * 8];   // x tile hi, K-blocked (24 KB)
    __shared__ unsigned short xl[24 * 64 * 8];   // x tile lo
    const int t    = threadIdx.x;
    const int bt1  = blockIdx.y;
    const int n0   = blockIdx.x * 64;
    const int w    = t >> 6;
    const int lane = t & 63;

    // interp rows c=0..127: one wave per 16 anchors, lanes = channels
    for (int nn = 0; nn < 16; ++nn) {
        int n = w * 16 + nn;
        size_t kb = ((size_t)bt1 * N1C + n0 + n) * 3;
        unsigned int u0 = nbr[kb], u1 = nbr[kb + 1], u2 = nbr[kb + 2];
        const float* p0 = tt + (size_t)(u0 >> 16) * CTC;
        const float* p1 = tt + (size_t)(u1 >> 16) * CTC;
        const float* p2 = tt + (size_t)(u2 >> 16) * CTC;
        float q0 = __half2float(__ushort_as_half((unsigned short)(u0 & 0xffffu)));
        float q1 = __half2float(__ushort_as_half((unsigned short)(u1 & 0xffffu)));
        float q2 = __half2float(__ushort_as_half((unsigned short)(u2 & 0xffffu)));
        float v0 = (p0[lane] * q0 + p1[lane] * q1) + p2[lane] * q2;
        float v1 = (p0[64 + lane] * q0 + p1[64 + lane] * q1) + p2[64 + lane] * q2;
        int c0 = lane;
        int bi0 = (((c0 >> 3) * 64) + n) * 8 + (c0 & 7);
        unsigned short h0 = bf16_hi(v0);
        xh[bi0] = h0; xl[bi0] = bf16_hi(v0 - bf16_to_f(h0));
        int c1 = 64 + lane;
        int bi1 = (((c1 >> 3) * 64) + n) * 8 + (c1 & 7);
        unsigned short h1 = bf16_hi(v1);
        xh[bi1] = h1; xl[bi1] = bf16_hi(v1 - bf16_to_f(h1));
    }
    // original_features rows c=128..191
    {
        const float* ofp = ofeat + (size_t)bt1 * CORIGC * N1C;
        for (int i = 0; i < 16; ++i) {
            int idx = i * 256 + t;
            int cp = idx >> 6, n = idx & 63;
            float v = ofp[(size_t)cp * N1C + n0 + n];
            int c = CTC + cp;
            int bi = (((c >> 3) * 64) + n) * 8 + (c & 7);
            unsigned short h = bf16_hi(v);
            xh[bi] = h; xl[bi] = bf16_hi(v - bf16_to_f(h));
        }
    }
    __syncthreads();

    const int l15  = lane & 15;
    const int quad = lane >> 4;
    const f32x4 zero = {0.f, 0.f, 0.f, 0.f};
    f32x4 acc[4][4];   // [mi = n-tile][oi = o-tile]
    for (int mi = 0; mi < 4; ++mi)
        for (int oi = 0; oi < 4; ++oi) acc[mi][oi] = zero;

    for (int kst = 0; kst < 6; ++kst) {
        bf16x8 ah[4], al[4], bh[4], bl[4];
        #pragma unroll
        for (int mi = 0; mi < 4; ++mi) {
            int n = mi * 16 + l15;
            int c8 = kst * 4 + quad;
            ah[mi] = *(const bf16x8*)&xh[(c8 * 64 + n) * 8];
            al[mi] = *(const bf16x8*)&xl[(c8 * 64 + n) * 8];
        }
        #pragma unroll
        for (int oi = 0; oi < 4; ++oi) {
            int o = w * 64 + oi * 16 + l15;
            bh[oi] = *(const bf16x8*)(WsH + (size_t)o * 192 + kst * 32 + quad * 8);
            bl[oi] = *(const bf16x8*)(WsL + (size_t)o * 192 + kst * 32 + quad * 8);
        }
        #pragma unroll
        for (int mi = 0; mi < 4; ++mi)
            #pragma unroll
            for (int oi = 0; oi < 4; ++oi) {
                acc[mi][oi] = MFMA16(ah[mi], bh[oi], acc[mi][oi]);
                acc[mi][oi] = MFMA16(ah[mi], bl[oi], acc[mi][oi]);
                acc[mi][oi] = MFMA16(al[mi], bh[oi], acc[mi][oi]);
            }
    }

    // epilogue: BN + ReLU, 4 consecutive n1 per lane -> dwordx4
    float* outp = out + OUT_XYZ_SIZE + (size_t)bt1 * CSC * N1C;
    #pragma unroll
    for (int oi = 0; oi < 4; ++oi) {
        int o = w * 64 + oi * 16 + l15;
        float sc = bnp[o], sh = bnp[CSC + o];
        #pragma unroll
        for (int mi = 0; mi < 4; ++mi) {
            int nb = n0 + mi * 16 + quad * 4;
            f32x4 y;
            y[0] = fmaxf(acc[mi][oi][0] * sc + sh, 0.f);
            y[1] = fmaxf(acc[mi][oi][1] * sc + sh, 0.f);
            y[2] = fmaxf(acc[mi][oi][2] * sc + sh, 0.f);
            y[3] = fmaxf(acc[mi][oi][3] * sc + sh, 0.f);
            *(f32x4*)&outp[(size_t)o * N1C + nb] = y;
        }
    }
}

// ---------------------------------------------------------------------------
extern "C" void kernel_launch(void* const* d_in, const int* in_sizes, int n_in,
                              void* d_out, int out_size, void* d_ws, size_t ws_size,
                              hipStream_t stream) {
    const float* xyzs  = (const float*)d_in[0];
    const float* oxyz  = (const float*)d_in[1];
    const float* feat  = (const float*)d_in[2];
    const float* ofeat = (const float*)d_in[3];
    const float* Wt0   = (const float*)d_in[4];
    const float* Wt1   = (const float*)d_in[5];
    const float* Wsm   = (const float*)d_in[6];
    const float* gam   = (const float*)d_in[7];
    const float* bet   = (const float*)d_in[8];
    const float* mu    = (const float*)d_in[9];
    const float* var   = (const float*)d_in[10];
    float* out = (float*)d_out;
    char*  wsb = (char*)d_ws;

    float*          tt  = (float*)(wsb + WS_TT_OFF);
    unsigned int*   nbr = (unsigned int*)(wsb + WS_NBR_OFF);
    unsigned short* WsH = (unsigned short*)(wsb + WS_W_OFF);
    unsigned short* WsL = WsH + 49152;
    unsigned short* W0H = WsL + 49152;
    unsigned short* W0L = W0H + 49152;
    unsigned short* W1H = W0L + 49152;
    unsigned short* W1L = W1H + 49152;
    float*          bnp = (float*)(wsb + WS_BNP_OFF);

    // Output 0: exact passthrough
    hipMemcpyAsync(out, oxyz, (size_t)OUT_XYZ_SIZE * sizeof(float),
                   hipMemcpyDeviceToDevice, stream);

    hipLaunchKernelGGL(prep_kernel, dim3(64), dim3(256), 0, stream,
                       Wsm, Wt0, Wt1, gam, bet, mu, var,
                       WsH, WsL, W0H, W0L, W1H, W1L, bnp);
    hipLaunchKernelGGL(tt_kernel, dim3(32, BB * L2C), dim3(256), 0, stream,
                       feat, W0H, W0L, W1H, W1L, tt);
    hipLaunchKernelGGL(knn_kernel, dim3(32, BB * L1C), dim3(256), 0, stream,
                       xyzs, oxyz, nbr);
    hipLaunchKernelGGL(out_kernel, dim3(128, BB * L1C), dim3(256), 0, stream,
                       ofeat, WsH, WsL, tt, nbr, bnp, out);
}

// Round 6
// 520.902 us; speedup vs baseline: 3.3496x; 1.5183x over previous
//
#include <hip/hip_runtime.h>
#include <hip/hip_bf16.h>
#include <hip/hip_fp16.h>

// Problem constants
#define BB 2
#define L2C 4
#define N2C 2048
#define L1C 9
#define N1C 8192
#define CINC 128
#define CTC 128
#define CSC 256
#define CORIGC 64
#define KC 3

#define OUT_XYZ_SIZE (BB*L1C*N1C*3)
#define FLT_BIG     3.402823466e38f

typedef __attribute__((ext_vector_type(8))) short bf16x8;
typedef __attribute__((ext_vector_type(4))) float f32x4;
typedef __attribute__((ext_vector_type(4))) unsigned short u16x4;

#define MFMA16(a,b,c) __builtin_amdgcn_mfma_f32_16x16x32_bf16((a),(b),(c),0,0,0)

// ws layout (bytes):
//  tt   bf16     @ 0          : 6,291,456 * 2 = 12,582,912
//  nbr  u32      @ 12,582,912 :   442,368 * 4 =  1,769,472   (idx16<<16 | half(w))
//  WsH/WsL/W0H/W0L/W1H/W1L bf16 @ 14,352,384 : 6 * 49,152 * 2 = 589,824
//  bnp  f32[512] @ 14,942,208 : 2,048
//  total 14,944,256
#define WS_TT_OFF   0
#define WS_NBR_OFF  12582912
#define WS_W_OFF    14352384
#define WS_BNP_OFF  14942208

__device__ __forceinline__ unsigned short bf16_hi(float v) {
    __hip_bfloat16 h = __float2bfloat16(v);
    return *(unsigned short*)&h;
}
__device__ __forceinline__ float bf16_to_f(unsigned short u) {
    unsigned int x = ((unsigned int)u) << 16;
    return __uint_as_float(x);
}
__device__ __forceinline__ float d2_exact(float dx, float dy, float dz) {
    #pragma clang fp contract(off)
    return (dx * dx + dy * dy) + dz * dz;
}

// ---------------------------------------------------------------------------
// Kernel P: hi/lo bf16 splits of Ws/Wt0/Wt1 (each 49152 elems) + BN fold.
__global__ __launch_bounds__(256) void prep_kernel(const float* __restrict__ Wsm,
                                                   const float* __restrict__ Wt0,
                                                   const float* __restrict__ Wt1,
                                                   const float* __restrict__ gam,
                                                   const float* __restrict__ bet,
                                                   const float* __restrict__ mu,
                                                   const float* __restrict__ var,
                                                   unsigned short* __restrict__ WsH,
                                                   unsigned short* __restrict__ WsL,
                                                   unsigned short* __restrict__ W0H,
                                                   unsigned short* __restrict__ W0L,
                                                   unsigned short* __restrict__ W1H,
                                                   unsigned short* __restrict__ W1L,
                                                   float* __restrict__ bnp) {
    for (int i = blockIdx.x * 256 + threadIdx.x; i < 49152; i += gridDim.x * 256) {
        float a = Wsm[i]; unsigned short h = bf16_hi(a);
        WsH[i] = h; WsL[i] = bf16_hi(a - bf16_to_f(h));
        float b = Wt0[i]; h = bf16_hi(b);
        W0H[i] = h; W0L[i] = bf16_hi(b - bf16_to_f(h));
        float c = Wt1[i]; h = bf16_hi(c);
        W1H[i] = h; W1L[i] = bf16_hi(c - bf16_to_f(h));
    }
    if (blockIdx.x == 0) {
        int o = threadIdx.x;
        float sc = gam[o] / sqrtf(var[o] + 1e-5f);
        bnp[o]       = sc;
        bnp[CSC + o] = bet[o] - mu[o] * sc;
    }
}

// ---------------------------------------------------------------------------
// Kernel 1 (MFMA): tt[slice][k][n2][c] = relu(W1[k] @ relu(W0[k] @ feat[slice]))
// tt stored bf16. grid (32 n-tiles of 64, 8 slices), 256 thr = 4 waves.
__global__ __launch_bounds__(256) void tt_kernel(const float* __restrict__ feat,
                                                 const unsigned short* __restrict__ W0H,
                                                 const unsigned short* __restrict__ W0L,
                                                 const unsigned short* __restrict__ W1H,
                                                 const unsigned short* __restrict__ W1L,
                                                 unsigned short* __restrict__ tt) {
    __shared__ unsigned short Bh[16 * 64 * 8];   // feat tile hi  (16 KB)
    __shared__ unsigned short Bl[16 * 64 * 8];   // feat tile lo
    __shared__ unsigned short Hh[16 * 64 * 8];   // layer-1 output hi
    const int t     = threadIdx.x;
    const int slice = blockIdx.y;
    const int n0    = blockIdx.x * 64;
    const int lane  = t & 63;
    const int w     = t >> 6;
    const int l15   = lane & 15;
    const int quad  = lane >> 4;

    const float* f = feat + (size_t)slice * CINC * N2C;
    for (int i = 0; i < 32; ++i) {
        int idx = i * 256 + t;
        int c = idx >> 6, n = idx & 63;
        float v = f[(size_t)c * N2C + n0 + n];
        unsigned short h = bf16_hi(v);
        int bi = (((c >> 3) * 64) + n) * 8 + (c & 7);
        Bh[bi] = h;
        Bl[bi] = bf16_hi(v - bf16_to_f(h));
    }
    __syncthreads();

    unsigned short* ttg = tt + (size_t)slice * KC * N2C * CTC;
    const f32x4 zero = {0.f, 0.f, 0.f, 0.f};

    for (int k = 0; k < KC; ++k) {
        // ---- layer 1 ----
        f32x4 acc[2][4];
        for (int oi = 0; oi < 2; ++oi)
            for (int ni = 0; ni < 4; ++ni) acc[oi][ni] = zero;
        {
            const unsigned short* AH = W0H + (size_t)k * CTC * CINC;
            const unsigned short* AL = W0L + (size_t)k * CTC * CINC;
            for (int kst = 0; kst < 4; ++kst) {
                bf16x8 ah[2], al[2], bh[4], bl[4];
                #pragma unroll
                for (int oi = 0; oi < 2; ++oi) {
                    int o = 32 * w + oi * 16 + l15;
                    ah[oi] = *(const bf16x8*)(AH + (size_t)o * CINC + kst * 32 + quad * 8);
                    al[oi] = *(const bf16x8*)(AL + (size_t)o * CINC + kst * 32 + quad * 8);
                }
                #pragma unroll
                for (int ni = 0; ni < 4; ++ni) {
                    int n = ni * 16 + l15;
                    int c8 = kst * 4 + quad;
                    bh[ni] = *(const bf16x8*)&Bh[(c8 * 64 + n) * 8];
                    bl[ni] = *(const bf16x8*)&Bl[(c8 * 64 + n) * 8];
                }
                #pragma unroll
                for (int oi = 0; oi < 2; ++oi)
                    #pragma unroll
                    for (int ni = 0; ni < 4; ++ni) {
                        acc[oi][ni] = MFMA16(ah[oi], bh[ni], acc[oi][ni]);
                        acc[oi][ni] = MFMA16(ah[oi], bl[ni], acc[oi][ni]);
                        acc[oi][ni] = MFMA16(al[oi], bh[ni], acc[oi][ni]);
                    }
            }
        }
        #pragma unroll
        for (int oi = 0; oi < 2; ++oi)
            #pragma unroll
            for (int ni = 0; ni < 4; ++ni) {
                int n = ni * 16 + l15;
                int obase = 32 * w + oi * 16 + quad * 4;
                int ch = obase >> 3, jj = obase & 7;
                unsigned short* dst = &Hh[(ch * 64 + n) * 8 + jj];
                dst[0] = bf16_hi(fmaxf(acc[oi][ni][0], 0.f));
                dst[1] = bf16_hi(fmaxf(acc[oi][ni][1], 0.f));
                dst[2] = bf16_hi(fmaxf(acc[oi][ni][2], 0.f));
                dst[3] = bf16_hi(fmaxf(acc[oi][ni][3], 0.f));
            }
        __syncthreads();

        // ---- layer 2 ----
        f32x4 acc2[2][4];
        for (int oi = 0; oi < 2; ++oi)
            for (int ni = 0; ni < 4; ++ni) acc2[oi][ni] = zero;
        {
            const unsigned short* AH = W1H + (size_t)k * CTC * CTC;
            const unsigned short* AL = W1L + (size_t)k * CTC * CTC;
            for (int kst = 0; kst < 4; ++kst) {
                bf16x8 ah[2], al[2], bh[4];
                #pragma unroll
                for (int oi = 0; oi < 2; ++oi) {
                    int o = 32 * w + oi * 16 + l15;
                    ah[oi] = *(const bf16x8*)(AH + (size_t)o * CTC + kst * 32 + quad * 8);
                    al[oi] = *(const bf16x8*)(AL + (size_t)o * CTC + kst * 32 + quad * 8);
                }
                #pragma unroll
                for (int ni = 0; ni < 4; ++ni) {
                    int n = ni * 16 + l15;
                    int c8 = kst * 4 + quad;
                    bh[ni] = *(const bf16x8*)&Hh[(c8 * 64 + n) * 8];
                }
                #pragma unroll
                for (int oi = 0; oi < 2; ++oi)
                    #pragma unroll
                    for (int ni = 0; ni < 4; ++ni) {
                        acc2[oi][ni] = MFMA16(ah[oi], bh[ni], acc2[oi][ni]);
                        acc2[oi][ni] = MFMA16(al[oi], bh[ni], acc2[oi][ni]);
                    }
            }
        }
        // relu + bf16 store: tt[k][n2][o], 4 consecutive o per lane -> 8B store
        #pragma unroll
        for (int oi = 0; oi < 2; ++oi)
            #pragma unroll
            for (int ni = 0; ni < 4; ++ni) {
                int n2 = n0 + ni * 16 + l15;
                int obase = 32 * w + oi * 16 + quad * 4;
                u16x4 vv;
                vv[0] = bf16_hi(fmaxf(acc2[oi][ni][0], 0.f));
                vv[1] = bf16_hi(fmaxf(acc2[oi][ni][1], 0.f));
                vv[2] = bf16_hi(fmaxf(acc2[oi][ni][2], 0.f));
                vv[3] = bf16_hi(fmaxf(acc2[oi][ni][3], 0.f));
                *(u16x4*)&ttg[((size_t)k * N2C + n2) * CTC + obase] = vv;
            }
        __syncthreads();
    }
}

// ---------------------------------------------------------------------------
// Kernel 2: 3-NN, 4 threads per anchor. grid (128 tiles of 64 anchors, 18 bt1).
// Each thread scans S/4 seeds (x8 unrolled, float4 LDS loads), partial top-3
// merged lexicographically by (d, idx) == np stable top-k semantics.
__global__ __launch_bounds__(256) void knn_kernel(const float* __restrict__ xyzs,
                                                  const float* __restrict__ oxyz,
                                                  unsigned int* __restrict__ nbr) {
    __shared__ __align__(16) float sx[4096];
    __shared__ __align__(16) float sy[4096];
    __shared__ __align__(16) float sz[4096];
    float* candd = sx;            // overlay after scan: [64][4][3]
    int*   candi = (int*)sy;
    const int t   = threadIdx.x;
    const int bt1 = blockIdx.y;
    const int b   = bt1 / L1C;
    const int t1  = bt1 % L1C + 1;
    int t2min = (t1 - 2) >> 1; if (t2min < 0) t2min = 0;
    int t2max = (t1 - 1) >> 1; if (t2max > 3) t2max = 3;
    const int S = (t2max - t2min + 1) * N2C;

    for (int s = t; s < S; s += 256) {
        int t2 = t2min + (s >> 11);
        int n2 = s & 2047;
        const float* p = xyzs + ((size_t)(b * L2C + t2) * N2C + n2) * 3;
        sx[s] = p[0]; sy[s] = p[1]; sz[s] = p[2];
    }
    __syncthreads();

    const int a  = t & 63;
    const int p  = t >> 6;
    const int n1 = blockIdx.x * 64 + a;
    const float* ap = oxyz + ((size_t)bt1 * N1C + n1) * 3;
    const float ax = ap[0], ay = ap[1], az = ap[2];

    float b0 = FLT_BIG, b1 = FLT_BIG, b2 = FLT_BIG;
    int   i0 = 0, i1 = 0, i2 = 0;
    const int chunk = S >> 2;
    const int start = p * chunk;

    for (int s8 = start; s8 < start + chunk; s8 += 8) {
        float4 x0 = *(const float4*)&sx[s8], x1 = *(const float4*)&sx[s8 + 4];
        float4 y0 = *(const float4*)&sy[s8], y1 = *(const float4*)&sy[s8 + 4];
        float4 z0 = *(const float4*)&sz[s8], z1 = *(const float4*)&sz[s8 + 4];
        float d[8];
        d[0] = d2_exact(ax - x0.x, ay - y0.x, az - z0.x);
        d[1] = d2_exact(ax - x0.y, ay - y0.y, az - z0.y);
        d[2] = d2_exact(ax - x0.z, ay - y0.z, az - z0.z);
        d[3] = d2_exact(ax - x0.w, ay - y0.w, az - z0.w);
        d[4] = d2_exact(ax - x1.x, ay - y1.x, az - z1.x);
        d[5] = d2_exact(ax - x1.y, ay - y1.y, az - z1.y);
        d[6] = d2_exact(ax - x1.z, ay - y1.z, az - z1.z);
        d[7] = d2_exact(ax - x1.w, ay - y1.w, az - z1.w);
        #pragma unroll
        for (int j = 0; j < 8; ++j) {
            float d2v = d[j];
            int s = s8 + j;
            if (d2v < b2) {
                if (d2v < b1) {
                    b2 = b1; i2 = i1;
                    if (d2v < b0) { b1 = b0; i1 = i0; b0 = d2v; i0 = s; }
                    else          { b1 = d2v; i1 = s; }
                } else { b2 = d2v; i2 = s; }
            }
        }
    }
    __syncthreads();   // all scans done; sx/sy reusable as candidate store

    candd[(a * 4 + p) * 3 + 0] = b0; candi[(a * 4 + p) * 3 + 0] = i0;
    candd[(a * 4 + p) * 3 + 1] = b1; candi[(a * 4 + p) * 3 + 1] = i1;
    candd[(a * 4 + p) * 3 + 2] = b2; candi[(a * 4 + p) * 3 + 2] = i2;
    __syncthreads();

    if (t < 64) {
        float dd[12]; int ii[12];
        for (int q = 0; q < 12; ++q) { dd[q] = candd[t * 12 + q]; ii[q] = candi[t * 12 + q]; }
        for (int x = 1; x < 12; ++x) {
            float dv = dd[x]; int iv = ii[x]; int y = x - 1;
            while (y >= 0 && (dd[y] > dv || (dd[y] == dv && ii[y] > iv))) {
                dd[y + 1] = dd[y]; ii[y + 1] = ii[y]; --y;
            }
            dd[y + 1] = dv; ii[y + 1] = iv;
        }
        float w0 = 1.f / (dd[0] + 1e-8f);
        float w1 = 1.f / (dd[1] + 1e-8f);
        float w2 = 1.f / (dd[2] + 1e-8f);
        float wsum = (w0 + w1) + w2;
        float wv[3] = { w0 / wsum, w1 / wsum, w2 / wsum };
        size_t base = ((size_t)bt1 * N1C + blockIdx.x * 64 + t) * 3;
        #pragma unroll
        for (int j = 0; j < 3; ++j) {
            int s  = ii[j];
            int t2 = t2min + (s >> 11);
            int n2 = s & 2047;
            int kidx = t1 - 2 * t2 - 1;
            unsigned int idx16 = (unsigned int)(((b * L2C + t2) * KC + kidx) * N2C + n2);
            unsigned short hb = __half_as_ushort(__float2half(wv[j]));
            nbr[base + j] = (idx16 << 16) | (unsigned int)hb;
        }
    }
}

// ---------------------------------------------------------------------------
// Kernel 3 (MFMA): gather-interp (bf16 tt, paired-channel u32 loads) + concat
// + GEMM(o=256, k=192) + BN + ReLU. grid (128 n-tiles of 64, 18 bt1).
__global__ __launch_bounds__(256) void out_kernel(const float* __restrict__ ofeat,
                                                  const unsigned short* __restrict__ WsH,
                                                  const unsigned short* __restrict__ WsL,
                                                  const unsigned short* __restrict__ tt,
                                                  const unsigned int* __restrict__ nbr,
                                                  const float* __restrict__ bnp,
                                                  float* __restrict__ out) {
    __shared__ unsigned short xh[24 * 64 * 8];   // x tile hi, K-blocked (24 KB)
    __shared__ unsigned short xl[24 * 64 * 8];   // x tile lo
    const int t    = threadIdx.x;
    const int bt1  = blockIdx.y;
    const int n0   = blockIdx.x * 64;
    const int w    = t >> 6;
    const int lane = t & 63;

    // interp rows: lane handles channel pair (2*lane, 2*lane+1)
    const int c0 = 2 * lane;
    for (int nn = 0; nn < 16; ++nn) {
        int n = w * 16 + nn;
        size_t kb = ((size_t)bt1 * N1C + n0 + n) * 3;
        unsigned int u0 = nbr[kb], u1 = nbr[kb + 1], u2 = nbr[kb + 2];
        const unsigned short* p0 = tt + (size_t)(u0 >> 16) * CTC;
        const unsigned short* p1 = tt + (size_t)(u1 >> 16) * CTC;
        const unsigned short* p2 = tt + (size_t)(u2 >> 16) * CTC;
        float q0 = __half2float(__ushort_as_half((unsigned short)(u0 & 0xffffu)));
        float q1 = __half2float(__ushort_as_half((unsigned short)(u1 & 0xffffu)));
        float q2 = __half2float(__ushort_as_half((unsigned short)(u2 & 0xffffu)));
        unsigned int g0 = *(const unsigned int*)(p0 + c0);
        unsigned int g1 = *(const unsigned int*)(p1 + c0);
        unsigned int g2 = *(const unsigned int*)(p2 + c0);
        float vE = (bf16_to_f((unsigned short)(g0 & 0xffffu)) * q0
                  + bf16_to_f((unsigned short)(g1 & 0xffffu)) * q1)
                  + bf16_to_f((unsigned short)(g2 & 0xffffu)) * q2;
        float vO = (bf16_to_f((unsigned short)(g0 >> 16)) * q0
                  + bf16_to_f((unsigned short)(g1 >> 16)) * q1)
                  + bf16_to_f((unsigned short)(g2 >> 16)) * q2;
        int bi = (((c0 >> 3) * 64) + n) * 8 + (c0 & 7);   // even -> +1 adjacent
        unsigned short hE = bf16_hi(vE), hO = bf16_hi(vO);
        *(unsigned int*)&xh[bi] = (unsigned int)hE | ((unsigned int)hO << 16);
        unsigned short lE = bf16_hi(vE - bf16_to_f(hE));
        unsigned short lO = bf16_hi(vO - bf16_to_f(hO));
        *(unsigned int*)&xl[bi] = (unsigned int)lE | ((unsigned int)lO << 16);
    }
    // original_features rows c=128..191
    {
        const float* ofp = ofeat + (size_t)bt1 * CORIGC * N1C;
        for (int i = 0; i < 16; ++i) {
            int idx = i * 256 + t;
            int cp = idx >> 6, n = idx & 63;
            float v = ofp[(size_t)cp * N1C + n0 + n];
            int c = CTC + cp;
            int bi = (((c >> 3) * 64) + n) * 8 + (c & 7);
            unsigned short h = bf16_hi(v);
            xh[bi] = h; xl[bi] = bf16_hi(v - bf16_to_f(h));
        }
    }
    __syncthreads();

    const int l15  = lane & 15;
    const int quad = lane >> 4;
    const f32x4 zero = {0.f, 0.f, 0.f, 0.f};
    f32x4 acc[4][4];
    for (int mi = 0; mi < 4; ++mi)
        for (int oi = 0; oi < 4; ++oi) acc[mi][oi] = zero;

    for (int kst = 0; kst < 6; ++kst) {
        bf16x8 ah[4], al[4], bh[4], bl[4];
        #pragma unroll
        for (int mi = 0; mi < 4; ++mi) {
            int n = mi * 16 + l15;
            int c8 = kst * 4 + quad;
            ah[mi] = *(const bf16x8*)&xh[(c8 * 64 + n) * 8];
            al[mi] = *(const bf16x8*)&xl[(c8 * 64 + n) * 8];
        }
        #pragma unroll
        for (int oi = 0; oi < 4; ++oi) {
            int o = w * 64 + oi * 16 + l15;
            bh[oi] = *(const bf16x8*)(WsH + (size_t)o * 192 + kst * 32 + quad * 8);
            bl[oi] = *(const bf16x8*)(WsL + (size_t)o * 192 + kst * 32 + quad * 8);
        }
        #pragma unroll
        for (int mi = 0; mi < 4; ++mi)
            #pragma unroll
            for (int oi = 0; oi < 4; ++oi) {
                acc[mi][oi] = MFMA16(ah[mi], bh[oi], acc[mi][oi]);
                acc[mi][oi] = MFMA16(ah[mi], bl[oi], acc[mi][oi]);
                acc[mi][oi] = MFMA16(al[mi], bh[oi], acc[mi][oi]);
            }
    }

    float* outp = out + OUT_XYZ_SIZE + (size_t)bt1 * CSC * N1C;
    #pragma unroll
    for (int oi = 0; oi < 4; ++oi) {
        int o = w * 64 + oi * 16 + l15;
        float sc = bnp[o], sh = bnp[CSC + o];
        #pragma unroll
        for (int mi = 0; mi < 4; ++mi) {
            int nb = n0 + mi * 16 + quad * 4;
            f32x4 y;
            y[0] = fmaxf(acc[mi][oi][0] * sc + sh, 0.f);
            y[1] = fmaxf(acc[mi][oi][1] * sc + sh, 0.f);
            y[2] = fmaxf(acc[mi][oi][2] * sc + sh, 0.f);
            y[3] = fmaxf(acc[mi][oi][3] * sc + sh, 0.f);
            *(f32x4*)&outp[(size_t)o * N1C + nb] = y;
        }
    }
}

// ---------------------------------------------------------------------------
extern "C" void kernel_launch(void* const* d_in, const int* in_sizes, int n_in,
                              void* d_out, int out_size, void* d_ws, size_t ws_size,
                              hipStream_t stream) {
    const float* xyzs  = (const float*)d_in[0];
    const float* oxyz  = (const float*)d_in[1];
    const float* feat  = (const float*)d_in[2];
    const float* ofeat = (const float*)d_in[3];
    const float* Wt0   = (const float*)d_in[4];
    const float* Wt1   = (const float*)d_in[5];
    const float* Wsm   = (const float*)d_in[6];
    const float* gam   = (const float*)d_in[7];
    const float* bet   = (const float*)d_in[8];
    const float* mu    = (const float*)d_in[9];
    const float* var   = (const float*)d_in[10];
    float* out = (float*)d_out;
    char*  wsb = (char*)d_ws;

    unsigned short* tt  = (unsigned short*)(wsb + WS_TT_OFF);
    unsigned int*   nbr = (unsigned int*)(wsb + WS_NBR_OFF);
    unsigned short* WsH = (unsigned short*)(wsb + WS_W_OFF);
    unsigned short* WsL = WsH + 49152;
    unsigned short* W0H = WsL + 49152;
    unsigned short* W0L = W0H + 49152;
    unsigned short* W1H = W0L + 49152;
    unsigned short* W1L = W1H + 49152;
    float*          bnp = (float*)(wsb + WS_BNP_OFF);

    // Output 0: exact passthrough
    hipMemcpyAsync(out, oxyz, (size_t)OUT_XYZ_SIZE * sizeof(float),
                   hipMemcpyDeviceToDevice, stream);

    hipLaunchKernelGGL(prep_kernel, dim3(64), dim3(256), 0, stream,
                       Wsm, Wt0, Wt1, gam, bet, mu, var,
                       WsH, WsL, W0H, W0L, W1H, W1L, bnp);
    hipLaunchKernelGGL(tt_kernel, dim3(32, BB * L2C), dim3(256), 0, stream,
                       feat, W0H, W0L, W1H, W1L, tt);
    hipLaunchKernelGGL(knn_kernel, dim3(128, BB * L1C), dim3(256), 0, stream,
                       xyzs, oxyz, nbr);
    hipLaunchKernelGGL(out_kernel, dim3(128, BB * L1C), dim3(256), 0, stream,
                       ofeat, WsH, WsL, tt, nbr, bnp, out);
}